// Round 3
// baseline (1300.985 us; speedup 1.0000x reference)
//
#include <hip/hip_runtime.h>
#include <math.h>

// Problem constants (from reference setup_inputs)
constexpr int Bq = 32;
constexpr int Tq = 8192;
constexpr int Dq = 8;
constexpr int Qq = 8;
constexpr int Kq = 1024;
constexpr int NTOK = Bq * Tq;                         // 262144 tokens
constexpr float LOSS_SCALE = 0.25f / (float)(Bq * Tq * Dq);

// Round 3: wave-uniform codebook reads via the SCALAR pipe, no LDS.
// R1 was LDS-RF-writeback bound (broadcast ds_read_b128 still writes 1 KB to
// the VGPR file per wave); R2 traded that for occupancy and went latency-bound
// (2 waves/SIMD). Codeword k is wave-uniform -> let the compiler emit
// s_load_dwordx8 into SGPRs (32 B once, scalar pipe), keep 1 token/thread so
// all 4096 waves are resident (16/CU, 4/SIMD) and the vector pipe runs only
// the 13 VALU ops per (token,k) pair.
// d2 numerics are bit-identical to the passing R2 kernel: same memory values,
// same op order (seq mul/fma dot; cn precomputed with np's mul + seq adds;
// d2 = fmaf(dot,-2, rn+cn); strict '<' first-min).

// Precompute per-codeword squared norms into d_ws (Q*K floats = 32 KB).
__global__ void rvq_norms(const float* __restrict__ codebooks,
                          float* __restrict__ cnorm)
{
    int i = blockIdx.x * 256 + threadIdx.x;          // 0 .. Q*K-1 (8192)
    const float* c = codebooks + (size_t)i * Dq;
    float n = __fmul_rn(c[0], c[0]);
#pragma unroll
    for (int d = 1; d < Dq; ++d)
        n = __fadd_rn(n, __fmul_rn(c[d], c[d]));
    cnorm[i] = n;
}

typedef float v8f __attribute__((ext_vector_type(8)));

__global__ __launch_bounds__(256, 4)
void rvq_main(const float* __restrict__ x,
              const float* __restrict__ codebooks,
              const float* __restrict__ post_scale,
              const float* __restrict__ post_bias,
              const float* __restrict__ conv_w,
              const float* __restrict__ conv_b,
              const float* __restrict__ cnorm,
              float* __restrict__ out)
{
    const int tid = threadIdx.x;
    const int token = blockIdx.x * 256 + tid;        // grid covers NTOK

    // residual r = x[token]
    float r[Dq];
    {
        const float4* xp = reinterpret_cast<const float4*>(x + (size_t)token * Dq);
        float4 a = xp[0], b = xp[1];
        r[0]=a.x; r[1]=a.y; r[2]=a.z; r[3]=a.w;
        r[4]=b.x; r[5]=b.y; r[6]=b.z; r[7]=b.w;
    }

    float qsum[Dq];
#pragma unroll
    for (int d = 0; d < Dq; ++d) qsum[d] = 0.0f;
    float lossacc = 0.0f;

    float* out_quant = out;                               // [B*T*D]
    float* out_loss  = out + (size_t)NTOK * Dq;           // [1]
    float* out_codes = out_loss + 1;                      // [Q*B*T] as float

    for (int q = 0; q < Qq; ++q) {
        const float* cbq = codebooks + (size_t)q * Kq * Dq;
        const float* cnq = cnorm + (size_t)q * Kq;

        // residual norm (np order)
        float rn = __fmul_rn(r[0], r[0]);
#pragma unroll
        for (int d = 1; d < Dq; ++d)
            rn = __fadd_rn(rn, __fmul_rn(r[d], r[d]));

        float best = __builtin_inff();
        int bk = 0;
#pragma unroll 4
        for (int k = 0; k < Kq; ++k) {
            // k is loop-uniform; readfirstlane makes uniformity explicit so
            // the backend selects SMEM (s_load_dwordx8) for the 32B codeword.
            int ku = __builtin_amdgcn_readfirstlane(k);
            v8f c = *reinterpret_cast<const v8f*>(cbq + (size_t)ku * Dq);
            float cn = cnq[ku];

            float dot = __fmul_rn(r[0], c[0]);
            dot = fmaf(r[1], c[1], dot);
            dot = fmaf(r[2], c[2], dot);
            dot = fmaf(r[3], c[3], dot);
            dot = fmaf(r[4], c[4], dot);
            dot = fmaf(r[5], c[5], dot);
            dot = fmaf(r[6], c[6], dot);
            dot = fmaf(r[7], c[7], dot);
            float d2 = fmaf(dot, -2.0f, __fadd_rn(rn, cn));
            if (d2 < best) { best = d2; bk = k; }          // first-min wins ties
        }

        // gather chosen embed (divergent vector load, 32 B)
        float e[Dq];
        {
            const float4* c4 = reinterpret_cast<const float4*>(cbq + (size_t)bk * Dq);
            float4 a = c4[0], b = c4[1];
            e[0]=a.x; e[1]=a.y; e[2]=a.z; e[3]=a.w;
            e[4]=b.x; e[5]=b.y; e[6]=b.z; e[7]=b.w;
        }

        out_codes[(size_t)q * NTOK + token] = (float)bk;

        const float sc = post_scale[q];
        const float bi = post_bias[q];
#pragma unroll
        for (int d = 0; d < Dq; ++d) {
            float est = __fadd_rn(r[d], __fsub_rn(e[d], r[d]));
            qsum[d] = __fadd_rn(__fadd_rn(qsum[d], __fmul_rn(est, sc)), bi);
            float nr = __fsub_rn(r[d], e[d]);
            float df = __fsub_rn(nr, e[d]);
            lossacc = fmaf(df, df, lossacc);
            r[d] = nr;
        }
    }

    // ---- 1x1 conv epilogue ----
    float o[Dq];
#pragma unroll
    for (int e = 0; e < Dq; ++e) {
        float acc = __fmul_rn(qsum[0], conv_w[e * Dq + 0]);
#pragma unroll
        for (int d = 1; d < Dq; ++d)
            acc = fmaf(qsum[d], conv_w[e * Dq + d], acc);
        o[e] = __fadd_rn(acc, conv_b[e]);
    }
    {
        float4* op = reinterpret_cast<float4*>(out_quant + (size_t)token * Dq);
        op[0] = make_float4(o[0], o[1], o[2], o[3]);
        op[1] = make_float4(o[4], o[5], o[6], o[7]);
    }

    // ---- loss reduction: wave butterfly, one atomic per wave ----
    float v = lossacc;
#pragma unroll
    for (int off = 32; off >= 1; off >>= 1)
        v += __shfl_xor(v, off, 64);
    if ((tid & 63) == 0)
        atomicAdd(out_loss, v * LOSS_SCALE);
}

extern "C" void kernel_launch(void* const* d_in, const int* in_sizes, int n_in,
                              void* d_out, int out_size, void* d_ws, size_t ws_size,
                              hipStream_t stream) {
    const float* x     = (const float*)d_in[0];
    const float* cb    = (const float*)d_in[1];
    const float* ps    = (const float*)d_in[2];
    const float* pb    = (const float*)d_in[3];
    const float* cw    = (const float*)d_in[4];
    const float* cbias = (const float*)d_in[5];
    float* out   = (float*)d_out;
    float* cnorm = (float*)d_ws;                     // Q*K floats = 32 KB

    // zero the loss accumulator slot (d_out is poisoned before every call)
    hipMemsetAsync(out + (size_t)NTOK * Dq, 0, sizeof(float), stream);

    rvq_norms<<<dim3(Qq * Kq / 256), dim3(256), 0, stream>>>(cb, cnorm);
    rvq_main<<<dim3(NTOK / 256), dim3(256), 0, stream>>>(
        x, cb, ps, pb, cw, cbias, cnorm, out);
}

// Round 4
// 1256.938 us; speedup vs baseline: 1.0350x; 1.0350x over previous
//
#include <hip/hip_runtime.h>
#include <math.h>

// Problem constants (from reference setup_inputs)
constexpr int Bq = 32;
constexpr int Tq = 8192;
constexpr int Dq = 8;
constexpr int Qq = 8;
constexpr int Kq = 1024;
constexpr int NTOK = Bq * Tq;                         // 262144 tokens
constexpr float LOSS_SCALE = 0.25f / (float)(Bq * Tq * Dq);

// Round 4: R2 structure (2 tokens/thread, LDS codebook) + explicit software
// pipeline in the argmin loop. Model: t=2 LDS floor 492us, VALU floor ~390us,
// R2 measured 863us because 2 waves/SIMD expose ds_read latency. Fix = ILP:
// prefetch k-group i+1 into registers (8x ds_read_b128) before computing
// group i's 8 dot/d2 chains (~230cy VALU), hiding the latency in-wave.
// d2 numerics bit-identical to passing R2: same LDS values, same op order
// (seq mul/fma dot; d2 = fmaf(dot,-2, rn+cn); strict '<' first-min, k asc).
__global__ __launch_bounds__(256, 2)
void rvq_main(const float* __restrict__ x,
              const float* __restrict__ codebooks,
              const float* __restrict__ post_scale,
              const float* __restrict__ post_bias,
              const float* __restrict__ conv_w,
              const float* __restrict__ conv_b,
              float* __restrict__ out)
{
    __shared__ __align__(16) float s_cb[Kq * Dq];   // 32 KB codebook tile
    __shared__ float s_cn[Kq];                      // 4 KB codeword norms

    const int tid = threadIdx.x;
    const int tok0 = blockIdx.x * 512 + tid;
    const int tok1 = tok0 + 256;

    float r0[Dq], r1[Dq];
    {
        const float4* xp0 = reinterpret_cast<const float4*>(x + (size_t)tok0 * Dq);
        float4 a = xp0[0], b = xp0[1];
        r0[0]=a.x; r0[1]=a.y; r0[2]=a.z; r0[3]=a.w;
        r0[4]=b.x; r0[5]=b.y; r0[6]=b.z; r0[7]=b.w;
        const float4* xp1 = reinterpret_cast<const float4*>(x + (size_t)tok1 * Dq);
        float4 c = xp1[0], d = xp1[1];
        r1[0]=c.x; r1[1]=c.y; r1[2]=c.z; r1[3]=c.w;
        r1[4]=d.x; r1[5]=d.y; r1[6]=d.z; r1[7]=d.w;
    }

    float qs0[Dq], qs1[Dq];
#pragma unroll
    for (int d = 0; d < Dq; ++d) { qs0[d] = 0.0f; qs1[d] = 0.0f; }
    float lossacc = 0.0f;

    float* out_quant = out;                               // [B*T*D]
    float* out_loss  = out + (size_t)NTOK * Dq;           // [1]
    float* out_codes = out_loss + 1;                      // [Q*B*T] as float

    for (int q = 0; q < Qq; ++q) {
        // ---- stage codebook q into LDS (coalesced float4) ----
        {
            const float4* src = reinterpret_cast<const float4*>(
                codebooks + (size_t)q * Kq * Dq);
            float4* dst = reinterpret_cast<float4*>(s_cb);
#pragma unroll
            for (int i = 0; i < (Kq * Dq / 4) / 256; ++i)  // 8 iters
                dst[tid + i * 256] = src[tid + i * 256];
        }
        __syncthreads();

        // ---- per-codeword squared norms (np order) ----
#pragma unroll
        for (int i = 0; i < Kq / 256; ++i) {               // 4 iters
            int k = tid + i * 256;
            const float* c = s_cb + k * Dq;
            float n = __fmul_rn(c[0], c[0]);
#pragma unroll
            for (int d = 1; d < Dq; ++d)
                n = __fadd_rn(n, __fmul_rn(c[d], c[d]));
            s_cn[k] = n;
        }
        __syncthreads();

        // ---- residual norms ----
        float rn0 = __fmul_rn(r0[0], r0[0]);
        float rn1 = __fmul_rn(r1[0], r1[0]);
#pragma unroll
        for (int d = 1; d < Dq; ++d) {
            rn0 = __fadd_rn(rn0, __fmul_rn(r0[d], r0[d]));
            rn1 = __fadd_rn(rn1, __fmul_rn(r1[d], r1[d]));
        }

        // ---- argmin, software-pipelined: prefetch k-group+1 while computing ----
        float best0 = __builtin_inff(), best1 = __builtin_inff();
        int bk0 = 0, bk1 = 0;
        const float4* cb4 = reinterpret_cast<const float4*>(s_cb);

        float4 p[8];                     // prefetched 4 codewords
        float  pn[4];                    // prefetched 4 norms
#pragma unroll
        for (int j = 0; j < 4; ++j) {
            p[2*j]   = cb4[2*j];
            p[2*j+1] = cb4[2*j+1];
            pn[j]    = s_cn[j];
        }

        for (int k = 0; k < Kq; k += 4) {
            float4 c[8]; float cn[4];
#pragma unroll
            for (int j = 0; j < 8; ++j) c[j] = p[j];
#pragma unroll
            for (int j = 0; j < 4; ++j) cn[j] = pn[j];

            const int kp = (k + 4) & (Kq - 1);   // wrap: re-reads k=0 last iter
#pragma unroll
            for (int j = 0; j < 4; ++j) {
                p[2*j]   = cb4[2*(kp + j)];
                p[2*j+1] = cb4[2*(kp + j) + 1];
                pn[j]    = s_cn[kp + j];
            }

#pragma unroll
            for (int j = 0; j < 4; ++j) {
                const float4 ca = c[2*j], cb = c[2*j+1];
                const float cnk = cn[j];

                float dot0 = __fmul_rn(r0[0], ca.x);
                dot0 = fmaf(r0[1], ca.y, dot0);
                dot0 = fmaf(r0[2], ca.z, dot0);
                dot0 = fmaf(r0[3], ca.w, dot0);
                dot0 = fmaf(r0[4], cb.x, dot0);
                dot0 = fmaf(r0[5], cb.y, dot0);
                dot0 = fmaf(r0[6], cb.z, dot0);
                dot0 = fmaf(r0[7], cb.w, dot0);
                float d20 = fmaf(dot0, -2.0f, __fadd_rn(rn0, cnk));
                if (d20 < best0) { best0 = d20; bk0 = k + j; }

                float dot1 = __fmul_rn(r1[0], ca.x);
                dot1 = fmaf(r1[1], ca.y, dot1);
                dot1 = fmaf(r1[2], ca.z, dot1);
                dot1 = fmaf(r1[3], ca.w, dot1);
                dot1 = fmaf(r1[4], cb.x, dot1);
                dot1 = fmaf(r1[5], cb.y, dot1);
                dot1 = fmaf(r1[6], cb.z, dot1);
                dot1 = fmaf(r1[7], cb.w, dot1);
                float d21 = fmaf(dot1, -2.0f, __fadd_rn(rn1, cnk));
                if (d21 < best1) { best1 = d21; bk1 = k + j; }
            }
        }

        // ---- gather chosen embeds, update state ----
        const float sc = post_scale[q];
        const float bi = post_bias[q];

        out_codes[(size_t)q * NTOK + tok0] = (float)bk0;
        out_codes[(size_t)q * NTOK + tok1] = (float)bk1;

        {
            const float* cc = s_cb + bk0 * Dq;
#pragma unroll
            for (int d = 0; d < Dq; ++d) {
                float e = cc[d];
                float est = __fadd_rn(r0[d], __fsub_rn(e, r0[d]));
                qs0[d] = __fadd_rn(__fadd_rn(qs0[d], __fmul_rn(est, sc)), bi);
                float nr = __fsub_rn(r0[d], e);
                float df = __fsub_rn(nr, e);
                lossacc = fmaf(df, df, lossacc);
                r0[d] = nr;
            }
        }
        {
            const float* cc = s_cb + bk1 * Dq;
#pragma unroll
            for (int d = 0; d < Dq; ++d) {
                float e = cc[d];
                float est = __fadd_rn(r1[d], __fsub_rn(e, r1[d]));
                qs1[d] = __fadd_rn(__fadd_rn(qs1[d], __fmul_rn(est, sc)), bi);
                float nr = __fsub_rn(r1[d], e);
                float df = __fsub_rn(nr, e);
                lossacc = fmaf(df, df, lossacc);
                r1[d] = nr;
            }
        }
        __syncthreads();   // protects s_cb: prefetch reads done before restage
    }

    // ---- 1x1 conv epilogue ----
    {
        float o[Dq];
#pragma unroll
        for (int e = 0; e < Dq; ++e) {
            float acc = __fmul_rn(qs0[0], conv_w[e * Dq + 0]);
#pragma unroll
            for (int d = 1; d < Dq; ++d)
                acc = fmaf(qs0[d], conv_w[e * Dq + d], acc);
            o[e] = __fadd_rn(acc, conv_b[e]);
        }
        float4* op = reinterpret_cast<float4*>(out_quant + (size_t)tok0 * Dq);
        op[0] = make_float4(o[0], o[1], o[2], o[3]);
        op[1] = make_float4(o[4], o[5], o[6], o[7]);
    }
    {
        float o[Dq];
#pragma unroll
        for (int e = 0; e < Dq; ++e) {
            float acc = __fmul_rn(qs1[0], conv_w[e * Dq + 0]);
#pragma unroll
            for (int d = 1; d < Dq; ++d)
                acc = fmaf(qs1[d], conv_w[e * Dq + d], acc);
            o[e] = __fadd_rn(acc, conv_b[e]);
        }
        float4* op = reinterpret_cast<float4*>(out_quant + (size_t)tok1 * Dq);
        op[0] = make_float4(o[0], o[1], o[2], o[3]);
        op[1] = make_float4(o[4], o[5], o[6], o[7]);
    }

    // ---- loss reduction: wave butterfly, one atomic per wave ----
    float v = lossacc;
#pragma unroll
    for (int off = 32; off >= 1; off >>= 1)
        v += __shfl_xor(v, off, 64);
    if ((tid & 63) == 0)
        atomicAdd(out_loss, v * LOSS_SCALE);
}

extern "C" void kernel_launch(void* const* d_in, const int* in_sizes, int n_in,
                              void* d_out, int out_size, void* d_ws, size_t ws_size,
                              hipStream_t stream) {
    const float* x     = (const float*)d_in[0];
    const float* cb    = (const float*)d_in[1];
    const float* ps    = (const float*)d_in[2];
    const float* pb    = (const float*)d_in[3];
    const float* cw    = (const float*)d_in[4];
    const float* cbias = (const float*)d_in[5];
    float* out = (float*)d_out;

    // zero the loss accumulator slot (d_out is poisoned before every call)
    hipMemsetAsync(out + (size_t)NTOK * Dq, 0, sizeof(float), stream);

    rvq_main<<<dim3(NTOK / 512), dim3(256), 0, stream>>>(
        x, cb, ps, pb, cw, cbias, out);
}

// Round 5
// 717.778 us; speedup vs baseline: 1.8125x; 1.7512x over previous
//
#include <hip/hip_runtime.h>
#include <math.h>

// Problem constants (from reference setup_inputs)
constexpr int Bq = 32;
constexpr int Tq = 8192;
constexpr int Dq = 8;
constexpr int Qq = 8;
constexpr int Kq = 1024;
constexpr int NTOK = Bq * Tq;                         // 262144 tokens
constexpr float LOSS_SCALE = 0.25f / (float)(Bq * Tq * Dq);

// Round 5: t=2 tokens per LANE-PAIR with intra-wave split-K.
// Lanes i and i^32 hold the SAME two tokens; lo half scans k in [0,512),
// hi half k in [512,1024). This keeps R2's halved LDS traffic but doubles
// resident waves to 4096 (4/SIMD, 4 blocks/CU) — fixing R2's latency bound.
// The wave's ds_read has 2 distinct broadcast addresses = 2-way alias = free.
// Merge per q via __shfl_xor(32); strict '<' (hi ks all larger) preserves
// np.argmin first-min tie-break. d2 bits identical to passing R2 kernel.
__global__ __launch_bounds__(256, 4)
void rvq_main(const float* __restrict__ x,
              const float* __restrict__ codebooks,
              const float* __restrict__ post_scale,
              const float* __restrict__ post_bias,
              const float* __restrict__ conv_w,
              const float* __restrict__ conv_b,
              float* __restrict__ out)
{
    __shared__ __align__(16) float s_cb[Kq * Dq];   // 32 KB codebook tile
    __shared__ float s_cn[Kq];                      // 4 KB codeword norms

    const int tid  = threadIdx.x;
    const int lane = tid & 63;
    const int wave = tid >> 6;                      // 0..3
    const int half = lane >> 5;                     // 0 = k<512, 1 = k>=512
    const int sub  = lane & 31;
    const int pairid = wave * 32 + sub;             // 0..127
    const int tok0 = blockIdx.x * 256 + pairid;     // grid 1024 -> 256 tok/blk
    const int tok1 = tok0 + 128;
    const int kbase = half << 9;                    // 0 or 512

    float r0[Dq], r1[Dq];
    {
        const float4* xp0 = reinterpret_cast<const float4*>(x + (size_t)tok0 * Dq);
        float4 a = xp0[0], b = xp0[1];
        r0[0]=a.x; r0[1]=a.y; r0[2]=a.z; r0[3]=a.w;
        r0[4]=b.x; r0[5]=b.y; r0[6]=b.z; r0[7]=b.w;
        const float4* xp1 = reinterpret_cast<const float4*>(x + (size_t)tok1 * Dq);
        float4 c = xp1[0], d = xp1[1];
        r1[0]=c.x; r1[1]=c.y; r1[2]=c.z; r1[3]=c.w;
        r1[4]=d.x; r1[5]=d.y; r1[6]=d.z; r1[7]=d.w;
    }

    float qs0[Dq], qs1[Dq];
#pragma unroll
    for (int d = 0; d < Dq; ++d) { qs0[d] = 0.0f; qs1[d] = 0.0f; }
    float lossacc = 0.0f;

    float* out_quant = out;                               // [B*T*D]
    float* out_loss  = out + (size_t)NTOK * Dq;           // [1]
    float* out_codes = out_loss + 1;                      // [Q*B*T] as float

    for (int q = 0; q < Qq; ++q) {
        // ---- stage codebook q into LDS (coalesced float4) ----
        {
            const float4* src = reinterpret_cast<const float4*>(
                codebooks + (size_t)q * Kq * Dq);
            float4* dst = reinterpret_cast<float4*>(s_cb);
#pragma unroll
            for (int i = 0; i < (Kq * Dq / 4) / 256; ++i)  // 8 iters
                dst[tid + i * 256] = src[tid + i * 256];
        }
        __syncthreads();

        // ---- per-codeword squared norms (np order) ----
#pragma unroll
        for (int i = 0; i < Kq / 256; ++i) {               // 4 iters
            int k = tid + i * 256;
            const float* c = s_cb + k * Dq;
            float n = __fmul_rn(c[0], c[0]);
#pragma unroll
            for (int d = 1; d < Dq; ++d)
                n = __fadd_rn(n, __fmul_rn(c[d], c[d]));
            s_cn[k] = n;
        }
        __syncthreads();

        // ---- residual norms (np order) ----
        float rn0 = __fmul_rn(r0[0], r0[0]);
        float rn1 = __fmul_rn(r1[0], r1[0]);
#pragma unroll
        for (int d = 1; d < Dq; ++d) {
            rn0 = __fadd_rn(rn0, __fmul_rn(r0[d], r0[d]));
            rn1 = __fadd_rn(rn1, __fmul_rn(r1[d], r1[d]));
        }

        // ---- argmin over this half's 512 codewords ----
        float best0 = __builtin_inff(), best1 = __builtin_inff();
        int bk0 = kbase, bk1 = kbase;
        const float4* cb4 = reinterpret_cast<const float4*>(s_cb) + 2 * kbase;
        const float*  cnk = s_cn + kbase;
#pragma unroll 2
        for (int k = 0; k < Kq / 2; ++k) {
            float4 ca = cb4[2 * k];
            float4 cb = cb4[2 * k + 1];
            float cn = cnk[k];

            float dot0 = __fmul_rn(r0[0], ca.x);
            dot0 = fmaf(r0[1], ca.y, dot0);
            dot0 = fmaf(r0[2], ca.z, dot0);
            dot0 = fmaf(r0[3], ca.w, dot0);
            dot0 = fmaf(r0[4], cb.x, dot0);
            dot0 = fmaf(r0[5], cb.y, dot0);
            dot0 = fmaf(r0[6], cb.z, dot0);
            dot0 = fmaf(r0[7], cb.w, dot0);
            float d20 = fmaf(dot0, -2.0f, __fadd_rn(rn0, cn));
            if (d20 < best0) { best0 = d20; bk0 = kbase + k; }

            float dot1 = __fmul_rn(r1[0], ca.x);
            dot1 = fmaf(r1[1], ca.y, dot1);
            dot1 = fmaf(r1[2], ca.z, dot1);
            dot1 = fmaf(r1[3], ca.w, dot1);
            dot1 = fmaf(r1[4], cb.x, dot1);
            dot1 = fmaf(r1[5], cb.y, dot1);
            dot1 = fmaf(r1[6], cb.z, dot1);
            dot1 = fmaf(r1[7], cb.w, dot1);
            float d21 = fmaf(dot1, -2.0f, __fadd_rn(rn1, cn));
            if (d21 < best1) { best1 = d21; bk1 = kbase + k; }
        }

        // ---- merge halves: lo value wins ties (lower k = np first-min) ----
        {
            float ob0 = __shfl_xor(best0, 32, 64);
            int   obk0 = __shfl_xor(bk0, 32, 64);
            float ob1 = __shfl_xor(best1, 32, 64);
            int   obk1 = __shfl_xor(bk1, 32, 64);
            float lo_b0 = half ? ob0 : best0;  int lo_k0 = half ? obk0 : bk0;
            float hi_b0 = half ? best0 : ob0;  int hi_k0 = half ? bk0 : obk0;
            float lo_b1 = half ? ob1 : best1;  int lo_k1 = half ? obk1 : bk1;
            float hi_b1 = half ? best1 : ob1;  int hi_k1 = half ? bk1 : obk1;
            bk0 = (hi_b0 < lo_b0) ? hi_k0 : lo_k0;
            bk1 = (hi_b1 < lo_b1) ? hi_k1 : lo_k1;
        }

        // ---- gather chosen embeds, update state (both halves identically) ----
        const float sc = post_scale[q];
        const float bi = post_bias[q];

        if (half == 0) {
            out_codes[(size_t)q * NTOK + tok0] = (float)bk0;
            out_codes[(size_t)q * NTOK + tok1] = (float)bk1;
        }

        {
            const float* cc = s_cb + bk0 * Dq;
#pragma unroll
            for (int d = 0; d < Dq; ++d) {
                float e = cc[d];
                float est = __fadd_rn(r0[d], __fsub_rn(e, r0[d]));
                qs0[d] = __fadd_rn(__fadd_rn(qs0[d], __fmul_rn(est, sc)), bi);
                float nr = __fsub_rn(r0[d], e);
                float df = __fsub_rn(nr, e);
                if (half == 0) lossacc = fmaf(df, df, lossacc);
                r0[d] = nr;
            }
        }
        {
            const float* cc = s_cb + bk1 * Dq;
#pragma unroll
            for (int d = 0; d < Dq; ++d) {
                float e = cc[d];
                float est = __fadd_rn(r1[d], __fsub_rn(e, r1[d]));
                qs1[d] = __fadd_rn(__fadd_rn(qs1[d], __fmul_rn(est, sc)), bi);
                float nr = __fsub_rn(r1[d], e);
                float df = __fsub_rn(nr, e);
                if (half == 0) lossacc = fmaf(df, df, lossacc);
                r1[d] = nr;
            }
        }
        __syncthreads();   // before next q overwrites s_cb
    }

    // ---- 1x1 conv epilogue (lo half writes) ----
    if (half == 0) {
        {
            float o[Dq];
#pragma unroll
            for (int e = 0; e < Dq; ++e) {
                float acc = __fmul_rn(qs0[0], conv_w[e * Dq + 0]);
#pragma unroll
                for (int d = 1; d < Dq; ++d)
                    acc = fmaf(qs0[d], conv_w[e * Dq + d], acc);
                o[e] = __fadd_rn(acc, conv_b[e]);
            }
            float4* op = reinterpret_cast<float4*>(out_quant + (size_t)tok0 * Dq);
            op[0] = make_float4(o[0], o[1], o[2], o[3]);
            op[1] = make_float4(o[4], o[5], o[6], o[7]);
        }
        {
            float o[Dq];
#pragma unroll
            for (int e = 0; e < Dq; ++e) {
                float acc = __fmul_rn(qs1[0], conv_w[e * Dq + 0]);
#pragma unroll
                for (int d = 1; d < Dq; ++d)
                    acc = fmaf(qs1[d], conv_w[e * Dq + d], acc);
                o[e] = __fadd_rn(acc, conv_b[e]);
            }
            float4* op = reinterpret_cast<float4*>(out_quant + (size_t)tok1 * Dq);
            op[0] = make_float4(o[0], o[1], o[2], o[3]);
            op[1] = make_float4(o[4], o[5], o[6], o[7]);
        }
    }

    // ---- loss reduction: wave butterfly, one atomic per wave ----
    float v = lossacc;                                // hi half contributes 0
#pragma unroll
    for (int off = 32; off >= 1; off >>= 1)
        v += __shfl_xor(v, off, 64);
    if (lane == 0)
        atomicAdd(out_loss, v * LOSS_SCALE);
}

extern "C" void kernel_launch(void* const* d_in, const int* in_sizes, int n_in,
                              void* d_out, int out_size, void* d_ws, size_t ws_size,
                              hipStream_t stream) {
    const float* x     = (const float*)d_in[0];
    const float* cb    = (const float*)d_in[1];
    const float* ps    = (const float*)d_in[2];
    const float* pb    = (const float*)d_in[3];
    const float* cw    = (const float*)d_in[4];
    const float* cbias = (const float*)d_in[5];
    float* out = (float*)d_out;

    // zero the loss accumulator slot (d_out is poisoned before every call)
    hipMemsetAsync(out + (size_t)NTOK * Dq, 0, sizeof(float), stream);

    rvq_main<<<dim3(NTOK / 256), dim3(256), 0, stream>>>(
        x, cb, ps, pb, cw, cbias, out);
}

// Round 6
// 646.315 us; speedup vs baseline: 2.0129x; 1.1106x over previous
//
#include <hip/hip_runtime.h>
#include <math.h>

// Problem constants (from reference setup_inputs)
constexpr int Bq = 32;
constexpr int Tq = 8192;
constexpr int Dq = 8;
constexpr int Qq = 8;
constexpr int Kq = 1024;
constexpr int NTOK = Bq * Tq;                         // 262144 tokens
constexpr float LOSS_SCALE = 0.25f / (float)(Bq * Tq * Dq);

// Round 6: 4 tokens per lane x 4 k-slices, bank-skewed LDS.
// R5 was LDS-return-BW bound and its 2 k-halves hit the SAME banks (2-way
// conflict on every read; SQ_LDS_BANK_CONFLICT doubled). Here each ds_read
// feeds 4 tokens (9 B LDS per pair) and the 4 slices are skewed onto
// disjoint 8-bank groups: codeword k lives at float offset k*8 + (k>>8)*8
// (slice-to-slice stride 2056 = 8 mod 32), norms at k + (k>>8)*8.
// Waves stay 4096 (4/SIMD, 4 blocks/CU at 36.4 KB LDS).
// Merge across slices: 2-stage shfl_xor with exact lexicographic (d2,k) min
// -> np.argmin first-min tie-break. d2 numerics bit-identical to passing R5:
// same seq mul/fma dot, d2 = fmaf(dot,-2, rn+cn), strict '<', k ascending.
__global__ __launch_bounds__(256, 4)
void rvq_main(const float* __restrict__ x,
              const float* __restrict__ codebooks,
              const float* __restrict__ post_scale,
              const float* __restrict__ post_bias,
              const float* __restrict__ conv_w,
              const float* __restrict__ conv_b,
              float* __restrict__ out)
{
    __shared__ __align__(16) float s_cb[Kq * Dq + 32];  // skewed codebook
    __shared__ float s_cn[Kq + 32];                     // skewed norms

    const int tid   = threadIdx.x;
    const int lane  = tid & 63;
    const int wave  = tid >> 6;                    // 0..3
    const int slice = lane >> 4;                   // 0..3 -> k quarter
    const int sub   = lane & 15;                   // 0..15 -> token group
    const int kbase = slice << 8;                  // 0,256,512,768
    const int tbase = blockIdx.x * 256 + wave * 64 + sub;  // + 16*j, j=0..3

    // residuals: 4 tokens per lane (tokens sub+16j; duplicated across slices)
    float r[4][Dq];
#pragma unroll
    for (int j = 0; j < 4; ++j) {
        const float4* xp = reinterpret_cast<const float4*>(
            x + (size_t)(tbase + 16 * j) * Dq);
        float4 a = xp[0], b = xp[1];
        r[j][0]=a.x; r[j][1]=a.y; r[j][2]=a.z; r[j][3]=a.w;
        r[j][4]=b.x; r[j][5]=b.y; r[j][6]=b.z; r[j][7]=b.w;
    }

    // qsum only for the owned token (j == slice)
    float qso[Dq];
#pragma unroll
    for (int d = 0; d < Dq; ++d) qso[d] = 0.0f;
    float lossacc = 0.0f;

    float* out_quant = out;                               // [B*T*D]
    float* out_loss  = out + (size_t)NTOK * Dq;           // [1]
    float* out_codes = out_loss + 1;                      // [Q*B*T] as float

    for (int q = 0; q < Qq; ++q) {
        // ---- stage codebook q into LDS, skewed by region (k>>8) ----
        {
            const float4* src = reinterpret_cast<const float4*>(
                codebooks + (size_t)q * Kq * Dq);
            float4* dst = reinterpret_cast<float4*>(s_cb);
#pragma unroll
            for (int it = 0; it < (Kq * Dq / 4) / 256; ++it) {  // 8 iters
                int i = tid + it * 256;
                dst[i + ((i >> 9) << 1)] = src[i];  // +2 float4 per 256-cw region
            }
        }
        __syncthreads();

        // ---- per-codeword squared norms (np order), skewed store ----
#pragma unroll
        for (int it = 0; it < Kq / 256; ++it) {            // 4 iters
            int k = tid + it * 256;
            const float* c = s_cb + k * Dq + ((k >> 8) << 3);
            float n = __fmul_rn(c[0], c[0]);
#pragma unroll
            for (int d = 1; d < Dq; ++d)
                n = __fadd_rn(n, __fmul_rn(c[d], c[d]));
            s_cn[k + ((k >> 8) << 3)] = n;
        }
        __syncthreads();

        // ---- residual norms (np order) ----
        float rn[4];
#pragma unroll
        for (int j = 0; j < 4; ++j) {
            float n = __fmul_rn(r[j][0], r[j][0]);
#pragma unroll
            for (int d = 1; d < Dq; ++d)
                n = __fadd_rn(n, __fmul_rn(r[j][d], r[j][d]));
            rn[j] = n;
        }

        // ---- argmin over this slice's 256 codewords, 4 tokens per read ----
        float best[4];
        int   bk[4];
#pragma unroll
        for (int j = 0; j < 4; ++j) { best[j] = __builtin_inff(); bk[j] = kbase; }

        const float4* cb4 = reinterpret_cast<const float4*>(s_cb)
                            + (size_t)kbase * 2 + slice * 2;
        const float*  cnp = s_cn + kbase + slice * 8;
#pragma unroll 2
        for (int k = 0; k < Kq / 4; ++k) {
            float4 ca = cb4[2 * k];
            float4 cc = cb4[2 * k + 1];
            float cn = cnp[k];
            int cand = kbase + k;
#pragma unroll
            for (int j = 0; j < 4; ++j) {
                float dot = __fmul_rn(r[j][0], ca.x);
                dot = fmaf(r[j][1], ca.y, dot);
                dot = fmaf(r[j][2], ca.z, dot);
                dot = fmaf(r[j][3], ca.w, dot);
                dot = fmaf(r[j][4], cc.x, dot);
                dot = fmaf(r[j][5], cc.y, dot);
                dot = fmaf(r[j][6], cc.z, dot);
                dot = fmaf(r[j][7], cc.w, dot);
                float d2 = fmaf(dot, -2.0f, __fadd_rn(rn[j], cn));
                if (d2 < best[j]) { best[j] = d2; bk[j] = cand; }
            }
        }

        // ---- merge 4 slices: lexicographic (d2, k) min == np first-min ----
#pragma unroll
        for (int j = 0; j < 4; ++j) {
            float b = best[j]; int k = bk[j];
            {
                float ob = __shfl_xor(b, 16, 64);
                int   ok = __shfl_xor(k, 16, 64);
                if (ob < b || (ob == b && ok < k)) { b = ob; k = ok; }
            }
            {
                float ob = __shfl_xor(b, 32, 64);
                int   ok = __shfl_xor(k, 32, 64);
                if (ob < b || (ob == b && ok < k)) { b = ob; k = ok; }
            }
            best[j] = b; bk[j] = k;
        }

        const float sc = post_scale[q];
        const float bi = post_bias[q];

        // codes: lane writes its owned token (j == slice) -> fully coalesced
        out_codes[(size_t)q * NTOK + tbase + 16 * slice] = (float)bk[slice];

        // ---- update residuals (all 4 tokens); qsum/loss for owned only ----
#pragma unroll
        for (int j = 0; j < 4; ++j) {
            int kj = bk[j];
            const float* cc = s_cb + kj * Dq + ((kj >> 8) << 3);
#pragma unroll
            for (int d = 0; d < Dq; ++d) {
                float e = cc[d];
                float est = __fadd_rn(r[j][d], __fsub_rn(e, r[j][d]));
                if (j == slice)
                    qso[d] = __fadd_rn(__fadd_rn(qso[d], __fmul_rn(est, sc)), bi);
                float nr = __fsub_rn(r[j][d], e);
                float df = __fsub_rn(nr, e);
                if (j == slice) lossacc = fmaf(df, df, lossacc);
                r[j][d] = nr;
            }
        }
        __syncthreads();   // before next q overwrites s_cb
    }

    // ---- 1x1 conv epilogue: owned token only -> coalesced wave store ----
    {
        float o[Dq];
#pragma unroll
        for (int e = 0; e < Dq; ++e) {
            float acc = __fmul_rn(qso[0], conv_w[e * Dq + 0]);
#pragma unroll
            for (int d = 1; d < Dq; ++d)
                acc = fmaf(qso[d], conv_w[e * Dq + d], acc);
            o[e] = __fadd_rn(acc, conv_b[e]);
        }
        float4* op = reinterpret_cast<float4*>(
            out_quant + (size_t)(tbase + 16 * slice) * Dq);
        op[0] = make_float4(o[0], o[1], o[2], o[3]);
        op[1] = make_float4(o[4], o[5], o[6], o[7]);
    }

    // ---- loss reduction: each token counted once (owner lane) ----
    float v = lossacc;
#pragma unroll
    for (int off = 32; off >= 1; off >>= 1)
        v += __shfl_xor(v, off, 64);
    if (lane == 0)
        atomicAdd(out_loss, v * LOSS_SCALE);
}

extern "C" void kernel_launch(void* const* d_in, const int* in_sizes, int n_in,
                              void* d_out, int out_size, void* d_ws, size_t ws_size,
                              hipStream_t stream) {
    const float* x     = (const float*)d_in[0];
    const float* cb    = (const float*)d_in[1];
    const float* ps    = (const float*)d_in[2];
    const float* pb    = (const float*)d_in[3];
    const float* cw    = (const float*)d_in[4];
    const float* cbias = (const float*)d_in[5];
    float* out = (float*)d_out;

    // zero the loss accumulator slot (d_out is poisoned before every call)
    hipMemsetAsync(out + (size_t)NTOK * Dq, 0, sizeof(float), stream);

    rvq_main<<<dim3(NTOK / 256), dim3(256), 0, stream>>>(
        x, cb, ps, pb, cw, cbias, out);
}